// Round 6
// baseline (98.253 us; speedup 1.0000x reference)
//
#include <hip/hip_runtime.h>

// GALNLLLoss2d: fused 2x2 Cholesky-solve + log K1 Bessel NLL, mean-reduced.
// Inputs (f32): loc[B,2], m[B,2], L[B,2,2] (lower-tri, positive diag), x[B,2]
// Output: single f32 = -mean(log_prob)
// R6: R4's proven loader (float2/float4 per row, native v_rcp/v_log, 2-deep
//     batch) + single-kernel deterministic finish: 64 cache-line-spread int64
//     fixed-point slots + hierarchical counters (R3 died on ONE shared line;
//     this caps per-line serialization at 32 RMWs, lines run in parallel).

#define C_LOG2   0.6931471805599453f
#define C_LOG2PI 1.8378770664093453f
#define C_LN2    0.69314718055994530942f
#define FXSCALE  4294967296.0   // 2^32 fixed-point; |total*2^32| ~ 9e16 << 2^63
#define NGROUPS  64             // 64-byte-separated accumulator lines

__device__ __forceinline__ float fast_log(float v) {
    return __builtin_amdgcn_logf(v) * C_LN2;   // v_log_f32 is log2
}

__device__ __forceinline__ float gal_row(
    float2 l, float2 m, float2 x, float4 L)
{
    const float La = L.x, Lb = L.z, Lc = L.w;
    const float ia = __builtin_amdgcn_rcpf(La);
    const float ic = __builtin_amdgcn_rcpf(Lc);
    const float d0 = x.x - l.x, d1 = x.y - l.y;
    // y = L^{-1} v (forward substitution); v^T Sinv w = (L^{-1}v)·(L^{-1}w)
    const float ym0 = m.x * ia;
    const float ym1 = (m.y - Lb * ym0) * ic;
    const float yx0 = d0 * ia;
    const float yx1 = (d1 - Lb * yx0) * ic;
    const float qm  = ym0 * ym0 + ym1 * ym1;   // m^T Sinv m
    const float qx  = yx0 * yx0 + yx1 * yx1;   // diff^T Sinv diff
    const float qxm = yx0 * ym0 + yx1 * ym1;   // diff^T Sinv m
    const float s = 2.0f + qm;
    const float z = sqrtf(s * qx);

    // Branchless A&S 9.8.3/9.8.7/9.8.8 with clamped safe args.
    const float zs = fminf(z, 2.0f);
    float t = zs * 0.26666666666f;  // z/3.75
    t = t * t;
    const float i1 = zs * (0.5f + t * (0.87890594f + t * (0.51498869f
                   + t * (0.15084934f + t * (0.02658733f + t * (0.00301532f
                   + t * 0.00032411f))))));
    const float t2 = zs * zs * 0.25f;
    const float zk1 = zs * fast_log(zs * 0.5f) * i1 + 1.0f + t2 * (0.15443144f
                    + t2 * (-0.67278579f + t2 * (-0.18156897f
                    + t2 * (-0.01919402f + t2 * (-0.00110404f
                    + t2 * (-0.00004686f))))));
    const float zl = fmaxf(z, 2.0f);
    const float u = 2.0f * __builtin_amdgcn_rcpf(zl);
    const float poly = 1.25331414f + u * (0.23498619f + u * (-0.03655620f
                     + u * (0.01504268f + u * (-0.00780353f + u * (0.00325614f
                     + u * (-0.00068245f))))));
    const bool small = (z <= 2.0f);
    // Fold: -log(a*c) + 0.5*log(qx/s) + log(kve1) - z
    //   small: = log( zk1 / (s*a*c) )                 [z/zs cancels]
    //   large: = log( poly*sqrt(z) / (s*a*c) ) - z
    const float arg = small ? zk1 : poly * sqrtf(z);
    const float tail = small ? 0.0f : z;
    return C_LOG2 + qxm - C_LOG2PI
         + fast_log(arg * __builtin_amdgcn_rcpf(s * La * Lc)) - tail;
}

__global__ __launch_bounds__(256) void gal_main_kernel(
    const float2* __restrict__ loc2, const float2* __restrict__ m2,
    const float4* __restrict__ L4,   const float2* __restrict__ x2,
    char* __restrict__ ws, float* __restrict__ out,
    int n, double scale_out)
{
    float acc = 0.0f;
    const int stride = gridDim.x * blockDim.x;
    int i = blockIdx.x * blockDim.x + threadIdx.x;
    // 2-deep unconditional batch: issue all 8 loads, then compute both rows.
    for (; i + stride < n; i += 2 * stride) {
        const int j = i + stride;
        const float2 l0 = loc2[i], mm0 = m2[i], xx0 = x2[i];
        const float4 A0 = L4[i];
        const float2 l1 = loc2[j], mm1 = m2[j], xx1 = x2[j];
        const float4 A1 = L4[j];
        acc += gal_row(l0, mm0, xx0, A0);
        acc += gal_row(l1, mm1, xx1, A1);
    }
    if (i < n)
        acc += gal_row(loc2[i], m2[i], x2[i], L4[i]);

    // wave64 down-reduce (f32), then cross-wave via LDS
    #pragma unroll
    for (int off = 32; off > 0; off >>= 1)
        acc += __shfl_down(acc, off);
    __shared__ float smem[4];
    const int lane = threadIdx.x & 63;
    const int wid  = threadIdx.x >> 6;
    if (lane == 0) smem[wid] = acc;
    __syncthreads();
    if (threadIdx.x == 0) {
        const double bsum = (double)smem[0] + (double)smem[1]
                          + (double)smem[2] + (double)smem[3];
        const long long q = (long long)llrint(bsum * FXSCALE);
        const int g = blockIdx.x & (NGROUPS - 1);
        long long* accp = (long long*)(ws + (size_t)g * 64);
        int*       cntp = (int*)      (ws + (size_t)g * 64 + 8);
        int*       l2p  = (int*)      (ws + (size_t)NGROUPS * 64);
        // deterministic: int64 adds are associative/commutative
        __hip_atomic_fetch_add(accp, q, __ATOMIC_RELAXED,
                               __HIP_MEMORY_SCOPE_AGENT);
        const int per = (int)(gridDim.x >> 6);  // blocks per group
        const int old = __hip_atomic_fetch_add(cntp, 1, __ATOMIC_ACQ_REL,
                                               __HIP_MEMORY_SCOPE_AGENT);
        if (old == per - 1) {  // group leader: all 32 of this line are in
            const int old2 = __hip_atomic_fetch_add(l2p, 1, __ATOMIC_ACQ_REL,
                                                    __HIP_MEMORY_SCOPE_AGENT);
            if (old2 == NGROUPS - 1) {  // final leader: everything is in
                long long tot = 0;
                for (int k = 0; k < NGROUPS; ++k)
                    tot += __hip_atomic_load(
                        (long long*)(ws + (size_t)k * 64),
                        __ATOMIC_RELAXED, __HIP_MEMORY_SCOPE_AGENT);
                out[0] = (float)((double)tot * scale_out);
            }
        }
    }
}

extern "C" void kernel_launch(void* const* d_in, const int* in_sizes, int n_in,
                              void* d_out, int out_size, void* d_ws, size_t ws_size,
                              hipStream_t stream) {
    const float* loc = (const float*)d_in[0];
    const float* m   = (const float*)d_in[1];
    const float* L   = (const float*)d_in[2];
    const float* x   = (const float*)d_in[3];
    const int n = in_sizes[0] / 2;       // B rows

    hipMemsetAsync(d_ws, 0, NGROUPS * 64 + 64, stream);  // slots + counters

    const int nblocks = 2048;  // 8192 waves = chip capacity; 2048/64=32 per group
    const double scale_out = -1.0 / (FXSCALE * (double)n);
    gal_main_kernel<<<nblocks, 256, 0, stream>>>(
        (const float2*)loc, (const float2*)m, (const float4*)L,
        (const float2*)x, (char*)d_ws, (float*)d_out, n, scale_out);
}

// Round 7
// 34.717 us; speedup vs baseline: 2.8301x; 2.8301x over previous
//
#include <hip/hip_runtime.h>

// GALNLLLoss2d: fused 2x2 Cholesky-solve + log K1 Bessel NLL, mean-reduced.
// Inputs (f32): loc[B,2], m[B,2], L[B,2,2] (lower-tri, positive diag), x[B,2]
// Output: single f32 = -mean(log_prob)
// R7: two-kernel deterministic reduce (single-kernel agent-scope finishes cost
//     ~65us in L2 wb/inv fences -- R3/R6). Explicit 1-row software pipeline:
//     next row's loads issued before current row's compute. 1024x512 grid,
//     single-wave finalizer.

#define C_LOG2   0.6931471805599453f
#define C_LOG2PI 1.8378770664093453f
#define C_LN2    0.69314718055994530942f

__device__ __forceinline__ float fast_log(float v) {
    return __builtin_amdgcn_logf(v) * C_LN2;   // v_log_f32 is log2
}

__device__ __forceinline__ float gal_row(
    float2 l, float2 m, float2 x, float4 L)
{
    const float La = L.x, Lb = L.z, Lc = L.w;
    const float ia = __builtin_amdgcn_rcpf(La);
    const float ic = __builtin_amdgcn_rcpf(Lc);
    const float d0 = x.x - l.x, d1 = x.y - l.y;
    // y = L^{-1} v (forward substitution); v^T Sinv w = (L^{-1}v)·(L^{-1}w)
    const float ym0 = m.x * ia;
    const float ym1 = (m.y - Lb * ym0) * ic;
    const float yx0 = d0 * ia;
    const float yx1 = (d1 - Lb * yx0) * ic;
    const float qm  = ym0 * ym0 + ym1 * ym1;   // m^T Sinv m
    const float qx  = yx0 * yx0 + yx1 * yx1;   // diff^T Sinv diff
    const float qxm = yx0 * ym0 + yx1 * ym1;   // diff^T Sinv m
    const float s = 2.0f + qm;
    const float z = sqrtf(s * qx);

    // Branchless A&S 9.8.3/9.8.7/9.8.8 with clamped safe args.
    const float zs = fminf(z, 2.0f);
    float t = zs * 0.26666666666f;  // z/3.75
    t = t * t;
    const float i1 = zs * (0.5f + t * (0.87890594f + t * (0.51498869f
                   + t * (0.15084934f + t * (0.02658733f + t * (0.00301532f
                   + t * 0.00032411f))))));
    const float t2 = zs * zs * 0.25f;
    const float zk1 = zs * fast_log(zs * 0.5f) * i1 + 1.0f + t2 * (0.15443144f
                    + t2 * (-0.67278579f + t2 * (-0.18156897f
                    + t2 * (-0.01919402f + t2 * (-0.00110404f
                    + t2 * (-0.00004686f))))));
    const float zl = fmaxf(z, 2.0f);
    const float u = 2.0f * __builtin_amdgcn_rcpf(zl);
    const float poly = 1.25331414f + u * (0.23498619f + u * (-0.03655620f
                     + u * (0.01504268f + u * (-0.00780353f + u * (0.00325614f
                     + u * (-0.00068245f))))));
    const bool small = (z <= 2.0f);
    // Fold: -log(a*c) + 0.5*log(qx/s) + log(kve1) - z
    //   small: = log( zk1 / (s*a*c) )                 [z/zs cancels]
    //   large: = log( poly*sqrt(z) / (s*a*c) ) - z
    const float arg = small ? zk1 : poly * sqrtf(z);
    const float tail = small ? 0.0f : z;
    return C_LOG2 + qxm - C_LOG2PI
         + fast_log(arg * __builtin_amdgcn_rcpf(s * La * Lc)) - tail;
}

__global__ __launch_bounds__(512) void gal_main_kernel(
    const float2* __restrict__ loc2, const float2* __restrict__ m2,
    const float4* __restrict__ L4,   const float2* __restrict__ x2,
    float* __restrict__ partial, int n)
{
    float acc = 0.0f;
    const int stride = gridDim.x * blockDim.x;
    int i = blockIdx.x * blockDim.x + threadIdx.x;
    // Software pipeline: stage row i+stride while computing row i.
    if (i < n) {
        float2 l = loc2[i], mm = m2[i], xx = x2[i];
        float4 A = L4[i];
        int j = i + stride;
        for (; j < n; j += stride) {
            const float2 ln = loc2[j], mn = m2[j], xn = x2[j];
            const float4 An = L4[j];
            acc += gal_row(l, mm, xx, A);
            l = ln; mm = mn; xx = xn; A = An;
        }
        acc += gal_row(l, mm, xx, A);
    }

    // wave64 down-reduce (f32), then cross-wave via LDS
    #pragma unroll
    for (int off = 32; off > 0; off >>= 1)
        acc += __shfl_down(acc, off);
    __shared__ float smem[8];
    const int lane = threadIdx.x & 63;
    const int wid  = threadIdx.x >> 6;
    if (lane == 0) smem[wid] = acc;
    __syncthreads();
    if (threadIdx.x == 0) {
        float b = 0.0f;
        #pragma unroll
        for (int w = 0; w < 8; ++w) b += smem[w];
        partial[blockIdx.x] = b;
    }
}

__global__ __launch_bounds__(64) void gal_final_kernel(
    const float* __restrict__ partial, int nblocks,
    float* __restrict__ out, double inv_n)
{
    double acc = 0.0;
    for (int i = threadIdx.x; i < nblocks; i += 64)
        acc += (double)partial[i];
    #pragma unroll
    for (int off = 32; off > 0; off >>= 1)
        acc += __shfl_down(acc, off);
    if (threadIdx.x == 0)
        out[0] = (float)(-acc * inv_n);
}

extern "C" void kernel_launch(void* const* d_in, const int* in_sizes, int n_in,
                              void* d_out, int out_size, void* d_ws, size_t ws_size,
                              hipStream_t stream) {
    const float* loc = (const float*)d_in[0];
    const float* m   = (const float*)d_in[1];
    const float* L   = (const float*)d_in[2];
    const float* x   = (const float*)d_in[3];
    const int n = in_sizes[0] / 2;       // B rows

    int nblocks = 1024;  // 1024 x 512 = 524288 threads = 32 waves/CU
    const size_t need = (size_t)nblocks * sizeof(float);
    if (ws_size < need) nblocks = (int)(ws_size / sizeof(float));
    float* partial = (float*)d_ws;

    gal_main_kernel<<<nblocks, 512, 0, stream>>>(
        (const float2*)loc, (const float2*)m, (const float4*)L,
        (const float2*)x, partial, n);
    gal_final_kernel<<<1, 64, 0, stream>>>(partial, nblocks, (float*)d_out,
                                           1.0 / (double)n);
}